// Round 19
// baseline (214.491 us; speedup 1.0000x reference)
//
#include <hip/hip_runtime.h>
#include <cstddef>
#include <cstdint>

#define T_TOK 2048
#define HD 1024
#define ID 1024
#define NE 16
#define TOPK 4
#define BM 128          // pass2 tile
#define BN 128
#define BK 32
#define BM1 256         // pass1 tile
#define BN1 128
#define BK1 64
#define NK1 (HD / BK1)  // 16
#define MT_MAX 112      // 128-row tiles (pass2)
#define MT2_MAX 64      // 256-row tiles (pass1)
#define SLOT_CAP 16384

typedef float f32x4 __attribute__((ext_vector_type(4)));
typedef __bf16 bf16x8 __attribute__((ext_vector_type(8)));
typedef __bf16 bf16x4 __attribute__((ext_vector_type(4)));

// ---- workspace layout (bytes) ----
// w1b/w3b/w2b each hold 17 experts (slot 16 = shared expert).
#define WS_TILE_E 256                                   // int[MT_MAX]
#define WS_TILE_E2 2048                                 // int[MT2_MAX]
#define WS_LOGITS 4096                                  // float[2048*16]
#define WS_SLOT_TOK (WS_LOGITS + T_TOK * NE * 4)        // int[SLOT_CAP]
#define WS_SLOT_W (WS_SLOT_TOK + SLOT_CAP * 4)          // float[SLOT_CAP]
#define WS_H1 (WS_SLOT_W + SLOT_CAP * 4)                // bf16[SLOT_CAP][ID]
#define WS_XB (WS_H1 + (size_t)SLOT_CAP * ID * 2)       // bf16[T][H]
#define WS_W1B (WS_XB + (size_t)T_TOK * HD * 2)         // bf16 17*I*H
#define EXSZ ((size_t)ID * HD)

__device__ __forceinline__ f32x4 mfma16(bf16x8 a, bf16x8 b, f32x4 c) {
  return __builtin_amdgcn_mfma_f32_16x16x32_bf16(a, b, c, 0, 0, 0);
}

__device__ __forceinline__ bf16x4 pack4(f32x4 a) {
  bf16x4 o;
  o[0] = (__bf16)a[0]; o[1] = (__bf16)a[1]; o[2] = (__bf16)a[2]; o[3] = (__bf16)a[3];
  return o;
}

// async global(16B/lane) -> LDS, linear dest (m97 pattern)
__device__ __forceinline__ void gload16(const __bf16* g, __bf16* l) {
  __builtin_amdgcn_global_load_lds(
      (const __attribute__((address_space(1))) uint32_t*)g,
      (__attribute__((address_space(3))) uint32_t*)l, 16, 0, 0);
}

// 2048-f32x4 chunk cvt (256 thr): lane-adjacent 16B loads, MLP=8
__device__ __forceinline__ void cvt_chunk(const float* __restrict__ src,
                                          __bf16* __restrict__ dst, size_t off,
                                          int tid) {
  const f32x4* p = (const f32x4*)src + off + tid;
  __bf16* q = dst + 4 * (off + tid);
  f32x4 v0 = __builtin_nontemporal_load(p);
  f32x4 v1 = __builtin_nontemporal_load(p + 256);
  f32x4 v2 = __builtin_nontemporal_load(p + 512);
  f32x4 v3 = __builtin_nontemporal_load(p + 768);
  f32x4 v4 = __builtin_nontemporal_load(p + 1024);
  f32x4 v5 = __builtin_nontemporal_load(p + 1280);
  f32x4 v6 = __builtin_nontemporal_load(p + 1536);
  f32x4 v7 = __builtin_nontemporal_load(p + 1792);
  *(bf16x4*)(q + 0 * 1024) = pack4(v0);
  *(bf16x4*)(q + 1 * 1024) = pack4(v1);
  *(bf16x4*)(q + 2 * 1024) = pack4(v2);
  *(bf16x4*)(q + 3 * 1024) = pack4(v3);
  *(bf16x4*)(q + 4 * 1024) = pack4(v4);
  *(bf16x4*)(q + 5 * 1024) = pack4(v5);
  *(bf16x4*)(q + 6 * 1024) = pack4(v6);
  *(bf16x4*)(q + 7 * 1024) = pack4(v7);
}

#define W4 ((size_t)1 << 22)
#define S4 ((size_t)1 << 18)
#define X4 ((size_t)1 << 19)
#define LOGITS_BLOCKS (T_TOK / 4)
#define XCHUNKS ((int)(X4 / 2048))          // 256

// ---- fused_pre: router logits (512 blocks) + x cvt (256 blocks) ----------
__global__ __launch_bounds__(256) void fused_pre(
    const float* __restrict__ x, const float* __restrict__ gw,
    __bf16* __restrict__ xb, float* __restrict__ logits) {
  int tid = threadIdx.x;
  if ((int)blockIdx.x < LOGITS_BLOCKS) {
    int wv = tid >> 6;
    int lane = tid & 63;
    int tok = blockIdx.x * 4 + wv;
    int e = lane >> 2;
    int q = lane & 3;
    const float4* xr = (const float4*)(x + (size_t)tok * HD) + q * 64;
    const float4* wr = (const float4*)(gw + (size_t)e * HD) + q * 64;
    float s0 = 0.f, s1 = 0.f;
#pragma unroll 8
    for (int i = 0; i < 64; i += 2) {
      float4 a0 = xr[i], w0 = wr[i];
      float4 a1 = xr[i + 1], w1v = wr[i + 1];
      s0 += a0.x * w0.x + a0.y * w0.y + a0.z * w0.z + a0.w * w0.w;
      s1 += a1.x * w1v.x + a1.y * w1v.y + a1.z * w1v.z + a1.w * w1v.w;
    }
    float s = s0 + s1;
    s += __shfl_xor(s, 1);
    s += __shfl_xor(s, 2);
    if (q == 0) logits[(size_t)tok * NE + e] = s;
    return;
  }
  cvt_chunk(x, xb, (size_t)(blockIdx.x - LOGITS_BLOCKS) * 2048, tid);
}

// ---- router_cvt: block 0 = router_finish body; blocks 1.. = w1/w3/sw cvt --
#define RW_CHUNKS ((int)((2 * W4 + 2 * S4) / 2048))   // 4352
#define RC_GRID 2049

__global__ __launch_bounds__(256) void router_cvt(
    const float* __restrict__ logits, const float* __restrict__ bias,
    int* __restrict__ tile_e, int* __restrict__ tile_e2,
    int* __restrict__ slot_tok, float* __restrict__ slot_w,
    const float* __restrict__ w1, const float* __restrict__ w3,
    const float* __restrict__ sw1, const float* __restrict__ sw3,
    __bf16* __restrict__ w1b, __bf16* __restrict__ w3b) {
  int tid = threadIdx.x;
  if (blockIdx.x != 0) {
    for (size_t c = blockIdx.x - 1; c < RW_CHUNKS; c += RC_GRID - 1) {
      size_t f = c * 2048;
      const float* src;
      __bf16* dst;
      size_t off;
      if (f < W4) { src = w1; dst = w1b; off = f; }
      else if (f < 2 * W4) { src = w3; dst = w3b; off = f - W4; }
      else if (f < 2 * W4 + S4) { src = sw1; dst = w1b + 16 * EXSZ; off = f - 2 * W4; }
      else { src = sw3; dst = w3b + 16 * EXSZ; off = f - 2 * W4 - S4; }
      cvt_chunk(src, dst, off, tid);
    }
    return;
  }

  __shared__ int hist[NE];
  __shared__ int soff[NE + 1];
  __shared__ int fillp[NE];
  __shared__ unsigned lsel[T_TOK];
  __shared__ float4 lw4[T_TOK];

  if (tid < NE) { hist[tid] = 0; fillp[tid] = 0; }
  __syncthreads();

  float bb[NE];
#pragma unroll
  for (int e = 0; e < NE; ++e) bb[e] = bias[e];

  for (int j = 0; j < T_TOK / 256; ++j) {
    int t = tid + 256 * j;
    float lg[NE];
    const float4* lp = (const float4*)(logits + (size_t)t * NE);
#pragma unroll
    for (int q = 0; q < 4; ++q) {
      float4 v = lp[q];
      lg[4 * q] = v.x; lg[4 * q + 1] = v.y; lg[4 * q + 2] = v.z; lg[4 * q + 3] = v.w;
    }
    float b[NE];
#pragma unroll
    for (int e = 0; e < NE; ++e) b[e] = lg[e] + bb[e];

    int selk[TOPK];
    float raw[TOPK];
    unsigned used = 0;
#pragma unroll
    for (int k = 0; k < TOPK; ++k) {
      float best = -3.4e38f;
      int bi = 0;
#pragma unroll
      for (int e = 0; e < NE; ++e) {
        if (!((used >> e) & 1) && b[e] > best) { best = b[e]; bi = e; }
      }
      used |= (1u << bi);
      selk[k] = bi;
      raw[k] = lg[bi];
    }
    float m = raw[0];
#pragma unroll
    for (int k = 1; k < TOPK; ++k) m = fmaxf(m, raw[k]);
    float s = 0.f;
    float w[TOPK];
#pragma unroll
    for (int k = 0; k < TOPK; ++k) { w[k] = __expf(raw[k] - m); s += w[k]; }
    float inv = 1.f / s;
    lsel[t] = (unsigned)selk[0] | ((unsigned)selk[1] << 8) |
              ((unsigned)selk[2] << 16) | ((unsigned)selk[3] << 24);
    lw4[t] = make_float4(w[0] * inv, w[1] * inv, w[2] * inv, w[3] * inv);
#pragma unroll
    for (int k = 0; k < TOPK; ++k) atomicAdd(&hist[selk[k]], 1);
  }
  __syncthreads();

  if (tid == 0) {
    int o = 0;
    for (int e = 0; e < NE; ++e) { soff[e] = o; o += (hist[e] + BM1 - 1) & ~(BM1 - 1); }
    soff[NE] = o;
  }
  __syncthreads();
  int shared_base = soff[NE];
  int total = shared_base + T_TOK;
  for (int tt = tid; tt < MT_MAX; tt += 256) {
    int base = tt * BM;
    int ee = -1;
    if (base < shared_base) {
      ee = 0;
#pragma unroll
      for (int q = 1; q < NE; ++q) if (base >= soff[q]) ee = q;
    } else if (base < total) {
      ee = NE;
    }
    tile_e[tt] = ee;
  }
  for (int tt = tid; tt < MT2_MAX; tt += 256) {
    int base = tt * BM1;
    int ee = -1;
    if (base < shared_base) {
      ee = 0;
#pragma unroll
      for (int q = 1; q < NE; ++q) if (base >= soff[q]) ee = q;
    } else if (base < total) {
      ee = NE;
    }
    tile_e2[tt] = ee;
  }

  for (int j = 0; j < T_TOK / 256; ++j) {
    int t = tid + 256 * j;
    unsigned ps = lsel[t];
    float4 wv = lw4[t];
    int e0 = ps & 255, e1 = (ps >> 8) & 255, e2 = (ps >> 16) & 255, e3 = ps >> 24;
    int p0 = atomicAdd(&fillp[e0], 1);
    slot_tok[soff[e0] + p0] = t; slot_w[soff[e0] + p0] = wv.x;
    int p1 = atomicAdd(&fillp[e1], 1);
    slot_tok[soff[e1] + p1] = t; slot_w[soff[e1] + p1] = wv.y;
    int p2 = atomicAdd(&fillp[e2], 1);
    slot_tok[soff[e2] + p2] = t; slot_w[soff[e2] + p2] = wv.z;
    int p3 = atomicAdd(&fillp[e3], 1);
    slot_tok[soff[e3] + p3] = t; slot_w[soff[e3] + p3] = wv.w;
  }

  for (int s = tid; s < shared_base; s += 256) {
    int e = 0;
#pragma unroll
    for (int q = 1; q < NE; ++q) if (s >= soff[q]) e = q;
    if (s >= soff[e] + hist[e]) { slot_tok[s] = -1; slot_w[s] = 0.f; }
  }
  for (int s = shared_base + tid; s < total; s += 256) {
    slot_tok[s] = s - shared_base;
    slot_w[s] = 1.0f;
  }
}

// ===== pass 1 (r15/r18-proven) + T5 setprio around MFMA clusters ===========
// Co-resident w2-cvt tail blocks give wave role diversity -> setprio(1)
// prioritizes MFMA waves over cvt memory waves (m191 regime, not m190's).
#define P1_BLOCKS (8 * MT2_MAX)             // 512
#define W2CHUNKS ((int)((W4 + S4) / 4096))  // 1088 (512-thr chunks)

__global__ __launch_bounds__(512, 2) void pass1_bf16(
    const __bf16* __restrict__ xb, const int* __restrict__ slot_tok,
    const int* __restrict__ tile_e2, const __bf16* __restrict__ w1b,
    const __bf16* __restrict__ w3b, __bf16* __restrict__ h1,
    const float* __restrict__ w2, const float* __restrict__ sw2,
    __bf16* __restrict__ w2b) {
  int tid = threadIdx.x;
  int bid = blockIdx.x;
  if (bid >= P1_BLOCKS) {
    size_t f = (size_t)(bid - P1_BLOCKS) * 4096;
    const float* src;
    __bf16* dst;
    size_t off;
    if (f < W4) { src = w2; dst = w2b; off = f; }
    else { src = sw2; dst = w2b + 16 * EXSZ; off = f - W4; }
    const f32x4* p = (const f32x4*)src + off + tid;
    __bf16* q = dst + 4 * (off + tid);
    f32x4 v0 = __builtin_nontemporal_load(p);
    f32x4 v1 = __builtin_nontemporal_load(p + 512);
    f32x4 v2 = __builtin_nontemporal_load(p + 1024);
    f32x4 v3 = __builtin_nontemporal_load(p + 1536);
    f32x4 v4 = __builtin_nontemporal_load(p + 2048);
    f32x4 v5 = __builtin_nontemporal_load(p + 2560);
    f32x4 v6 = __builtin_nontemporal_load(p + 3072);
    f32x4 v7 = __builtin_nontemporal_load(p + 3584);
    *(bf16x4*)(q + 0 * 2048) = pack4(v0);
    *(bf16x4*)(q + 1 * 2048) = pack4(v1);
    *(bf16x4*)(q + 2 * 2048) = pack4(v2);
    *(bf16x4*)(q + 3 * 2048) = pack4(v3);
    *(bf16x4*)(q + 4 * 2048) = pack4(v4);
    *(bf16x4*)(q + 5 * 2048) = pack4(v5);
    *(bf16x4*)(q + 6 * 2048) = pack4(v6);
    *(bf16x4*)(q + 7 * 2048) = pack4(v7);
    return;
  }
  int nt = bid & 7;
  int mt = bid >> 3;
  int e = tile_e2[mt];
  if (e < 0) return;
  int n0 = nt * BN1;
  int m0 = mt * BM1;

  const __bf16* wg = w1b + (size_t)e * EXSZ;   // slot 16 = shared expert
  const __bf16* wu = w3b + (size_t)e * EXSZ;

  __shared__ __align__(16) __bf16 As[2][BM1 * BK1];  // 64 KB
  __shared__ __align__(16) __bf16 Bg[2][BN1 * BK1];  // 32 KB
  __shared__ __align__(16) __bf16 Bu[2][BN1 * BK1];  // 32 KB

  const __bf16* gA[4];
#pragma unroll
  for (int j = 0; j < 4; ++j) {
    int id = tid + j * 512;
    int r = id >> 3;
    int c = (id & 7) ^ (r & 7);
    int tok = slot_tok[m0 + r];
    if (tok < 0) tok = 0;
    gA[j] = xb + (size_t)tok * HD + c * 8;
  }
  const __bf16* gG[2];
  const __bf16* gU[2];
#pragma unroll
  for (int j = 0; j < 2; ++j) {
    int id = tid + j * 512;
    int r = id >> 3;
    int c = (id & 7) ^ (r & 7);
    gG[j] = wg + (size_t)(n0 + r) * HD + c * 8;
    gU[j] = wu + (size_t)(n0 + r) * HD + c * 8;
  }

  int wave = tid >> 6, lane = tid & 63;
  int wm = (wave >> 2) * 128;
  int wn = (wave & 3) * 32;
  int l16 = lane & 15, kch = lane >> 4;

  f32x4 accg[8][2] = {};
  f32x4 accu[8][2] = {};

  auto stage = [&](int B, int k0) {   // 8 gloads / thread
#pragma unroll
    for (int j = 0; j < 4; ++j)
      gload16(gA[j] + k0, &As[B][(size_t)(tid + j * 512) * 8]);
#pragma unroll
    for (int j = 0; j < 2; ++j) {
      gload16(gG[j] + k0, &Bg[B][(size_t)(tid + j * 512) * 8]);
      gload16(gU[j] + k0, &Bu[B][(size_t)(tid + j * 512) * 8]);
    }
  };

#pragma unroll 1
  for (int k = 0; k < NK1; ++k) {
    int buf = k & 1;
    if (k == 0) stage(0, 0);
    if (k + 1 < NK1) {
      stage(buf ^ 1, (k + 1) * BK1);
      asm volatile("s_waitcnt vmcnt(8)" ::: "memory");
    } else {
      asm volatile("s_waitcnt vmcnt(0)" ::: "memory");
    }
    __builtin_amdgcn_s_barrier();
    __builtin_amdgcn_sched_barrier(0);

#pragma unroll
    for (int s = 0; s < 2; ++s) {
      bf16x8 af[8], gf[2], uf[2];
#pragma unroll
      for (int i = 0; i < 8; ++i) {
        int R = wm + i * 16 + l16;
        int c = s * 4 + kch;
        af[i] = *(const bf16x8*)(&As[buf][R * BK1 + ((c ^ (R & 7)) * 8)]);
      }
#pragma unroll
      for (int i = 0; i < 2; ++i) {
        int R = wn + i * 16 + l16;
        int c = s * 4 + kch;
        gf[i] = *(const bf16x8*)(&Bg[buf][R * BK1 + ((c ^ (R & 7)) * 8)]);
        uf[i] = *(const bf16x8*)(&Bu[buf][R * BK1 + ((c ^ (R & 7)) * 8)]);
      }
      asm volatile("s_waitcnt lgkmcnt(0)" ::: "memory");
      if (s == 1) __builtin_amdgcn_s_barrier();
      __builtin_amdgcn_sched_barrier(0);         // rule #18
      __builtin_amdgcn_s_setprio(1);             // T5: favor MFMA waves
#pragma unroll
      for (int mi = 0; mi < 8; ++mi)
#pragma unroll
        for (int ni = 0; ni < 2; ++ni) {
          accg[mi][ni] = mfma16(af[mi], gf[ni], accg[mi][ni]);
          accu[mi][ni] = mfma16(af[mi], uf[ni], accu[mi][ni]);
        }
      __builtin_amdgcn_s_setprio(0);
    }
  }

#pragma unroll
  for (int mi = 0; mi < 8; ++mi) {
#pragma unroll
    for (int ni = 0; ni < 2; ++ni) {
#pragma unroll
      for (int j = 0; j < 4; ++j) {
        int row = m0 + wm + mi * 16 + kch * 4 + j;
        int col = n0 + wn + ni * 16 + l16;
        float g = accg[mi][ni][j];
        float u = accu[mi][ni][j];
        float hv = (g / (1.f + __expf(-g))) * u;
        h1[(size_t)row * ID + col] = (__bf16)hv;
      }
    }
  }
}

// ===== pass 2 (r14-proven) + T5 setprio (3 independent blocks/CU) ==========
__global__ __launch_bounds__(256, 3) void pass2_bf16(
    const __bf16* __restrict__ h1, const int* __restrict__ slot_tok,
    const float* __restrict__ slot_w, const int* __restrict__ tile_e,
    const __bf16* __restrict__ w2b, float* __restrict__ out) {
  int mt = blockIdx.y;
  int e = tile_e[mt];
  if (e < 0) return;
  int n0 = blockIdx.x * BN;
  int m0 = mt * BM;

  const __bf16* wd = w2b + (size_t)e * EXSZ;   // slot 16 = shared expert

  __shared__ __align__(16) __bf16 As[2][BM * BK];
  __shared__ __align__(16) __bf16 Bs[2][BN * BK];

  int tid = threadIdx.x;
  int r0 = tid >> 2, r1 = r0 + 64;
  int c8 = ((tid & 3) ^ ((r0 >> 1) & 3)) * 8;
  const __bf16* gA0 = h1 + (size_t)(m0 + r0) * ID + c8;
  const __bf16* gA1 = h1 + (size_t)(m0 + r1) * ID + c8;
  const __bf16* gB0 = wd + (size_t)(n0 + r0) * ID + c8;
  const __bf16* gB1 = wd + (size_t)(n0 + r1) * ID + c8;

  int wave = tid >> 6, lane = tid & 63;
  int wm = (wave >> 1) * 64, wn = (wave & 1) * 64;
  int l16 = lane & 15, kch = lane >> 4;
  int kk8 = (kch ^ ((l16 >> 1) & 3)) * 8;

  f32x4 acc[4][4] = {};

  auto stage = [&](int B, int k0) {
    gload16(gA0 + k0, &As[B][(size_t)tid * 8]);
    gload16(gA1 + k0, &As[B][(size_t)(tid + 256) * 8]);
    gload16(gB0 + k0, &Bs[B][(size_t)tid * 8]);
    gload16(gB1 + k0, &Bs[B][(size_t)(tid + 256) * 8]);
  };
  auto body = [&](int B) {
    bf16x8 af[4], bf[4];
#pragma unroll
    for (int i = 0; i < 4; ++i) {
      af[i] = *(const bf16x8*)(&As[B][(wm + i * 16 + l16) * BK + kk8]);
      bf[i] = *(const bf16x8*)(&Bs[B][(wn + i * 16 + l16) * BK + kk8]);
    }
    asm volatile("s_waitcnt lgkmcnt(0)" ::: "memory");
    __builtin_amdgcn_s_barrier();
    __builtin_amdgcn_sched_barrier(0);
    __builtin_amdgcn_s_setprio(1);             // T5
#pragma unroll
    for (int mi = 0; mi < 4; ++mi)
#pragma unroll
      for (int ni = 0; ni < 4; ++ni)
        acc[mi][ni] = mfma16(af[mi], bf[ni], acc[mi][ni]);
    __builtin_amdgcn_s_setprio(0);
  };

  stage(0, 0);
#pragma unroll 1
  for (int k = 0; k < ID / BK - 1; ++k) {
    int cur = k & 1;
    stage(cur ^ 1, (k + 1) * BK);
    asm volatile("s_waitcnt vmcnt(4)" ::: "memory");
    __builtin_amdgcn_s_barrier();
    __builtin_amdgcn_sched_barrier(0);
    body(cur);
  }
  asm volatile("s_waitcnt vmcnt(0)" ::: "memory");
  __builtin_amdgcn_s_barrier();
  __builtin_amdgcn_sched_barrier(0);
  body((ID / BK - 1) & 1);

#pragma unroll
  for (int mi = 0; mi < 4; ++mi) {
#pragma unroll
    for (int j = 0; j < 4; ++j) {
      int row = m0 + wm + mi * 16 + kch * 4 + j;
      int token = slot_tok[row];
      if (token < 0) continue;
      float wgt = slot_w[row];
#pragma unroll
      for (int ni = 0; ni < 4; ++ni) {
        int col = n0 + wn + ni * 16 + l16;
        atomicAdd(out + (size_t)token * HD + col, wgt * acc[mi][ni][j]);
      }
    }
  }
}

// ---------------- launcher ----------------
extern "C" void kernel_launch(void* const* d_in, const int* in_sizes, int n_in,
                              void* d_out, int out_size, void* d_ws, size_t ws_size,
                              hipStream_t stream) {
  const float* x = (const float*)d_in[0];
  const float* gate_w = (const float*)d_in[1];
  const float* ebias = (const float*)d_in[2];
  const float* w1 = (const float*)d_in[3];
  const float* w2 = (const float*)d_in[4];
  const float* w3 = (const float*)d_in[5];
  const float* sw1 = (const float*)d_in[6];
  const float* sw2 = (const float*)d_in[7];
  const float* sw3 = (const float*)d_in[8];
  float* out = (float*)d_out;

  char* ws = (char*)d_ws;
  int* tile_e = (int*)(ws + WS_TILE_E);
  int* tile_e2 = (int*)(ws + WS_TILE_E2);
  float* logits = (float*)(ws + WS_LOGITS);
  int* slot_tok = (int*)(ws + WS_SLOT_TOK);
  float* slot_w = (float*)(ws + WS_SLOT_W);
  __bf16* h1 = (__bf16*)(ws + WS_H1);
  __bf16* xb = (__bf16*)(ws + WS_XB);
  __bf16* w1b = (__bf16*)(ws + WS_W1B);       // 17 experts
  __bf16* w3b = w1b + 17 * EXSZ;              // 17 experts
  __bf16* w2b = w3b + 17 * EXSZ;              // 17 experts

  hipMemsetAsync(d_out, 0, (size_t)T_TOK * HD * sizeof(float), stream);

  fused_pre<<<LOGITS_BLOCKS + XCHUNKS, 256, 0, stream>>>(x, gate_w, xb, logits);
  router_cvt<<<RC_GRID, 256, 0, stream>>>(logits, ebias, tile_e, tile_e2,
                                          slot_tok, slot_w, w1, w3, sw1, sw3,
                                          w1b, w3b);
  pass1_bf16<<<P1_BLOCKS + W2CHUNKS, 512, 0, stream>>>(
      xb, slot_tok, tile_e2, w1b, w3b, h1, w2, sw2, w2b);
  pass2_bf16<<<dim3(HD / BN, MT_MAX), 256, 0, stream>>>(
      h1, slot_tok, slot_w, tile_e, w2b, out);
}

// Round 20
// 208.391 us; speedup vs baseline: 1.0293x; 1.0293x over previous
//
#include <hip/hip_runtime.h>
#include <cstddef>
#include <cstdint>

#define T_TOK 2048
#define HD 1024
#define ID 1024
#define NE 16
#define TOPK 4
#define BM 128          // pass2 tile
#define BN 128
#define BK 32
#define BM1 256         // pass1 tile
#define BN1 128
#define BK1 64
#define NK1 (HD / BK1)  // 16
#define MT_MAX 112      // 128-row tiles (pass2)
#define MT2_MAX 64      // 256-row tiles (pass1)
#define SLOT_CAP 16384

typedef float f32x4 __attribute__((ext_vector_type(4)));
typedef __bf16 bf16x8 __attribute__((ext_vector_type(8)));
typedef __bf16 bf16x4 __attribute__((ext_vector_type(4)));

// ---- workspace layout (bytes) ----
// w1b/w3b/w2b each hold 17 experts (slot 16 = shared expert).
#define WS_TILE_E 256                                   // int[MT_MAX]
#define WS_TILE_E2 2048                                 // int[MT2_MAX]
#define WS_LOGITS 4096                                  // float[2048*16]
#define WS_SLOT_TOK (WS_LOGITS + T_TOK * NE * 4)        // int[SLOT_CAP]
#define WS_SLOT_W (WS_SLOT_TOK + SLOT_CAP * 4)          // float[SLOT_CAP]
#define WS_H1 (WS_SLOT_W + SLOT_CAP * 4)                // bf16[SLOT_CAP][ID]
#define WS_XB (WS_H1 + (size_t)SLOT_CAP * ID * 2)       // bf16[T][H]
#define WS_W1B (WS_XB + (size_t)T_TOK * HD * 2)         // bf16 17*I*H
#define EXSZ ((size_t)ID * HD)

__device__ __forceinline__ f32x4 mfma16(bf16x8 a, bf16x8 b, f32x4 c) {
  return __builtin_amdgcn_mfma_f32_16x16x32_bf16(a, b, c, 0, 0, 0);
}

__device__ __forceinline__ bf16x4 pack4(f32x4 a) {
  bf16x4 o;
  o[0] = (__bf16)a[0]; o[1] = (__bf16)a[1]; o[2] = (__bf16)a[2]; o[3] = (__bf16)a[3];
  return o;
}

// async global(16B/lane) -> LDS, linear dest (m97 pattern)
__device__ __forceinline__ void gload16(const __bf16* g, __bf16* l) {
  __builtin_amdgcn_global_load_lds(
      (const __attribute__((address_space(1))) uint32_t*)g,
      (__attribute__((address_space(3))) uint32_t*)l, 16, 0, 0);
}

// 2048-f32x4 chunk cvt (256 thr): lane-adjacent 16B loads, MLP=8
__device__ __forceinline__ void cvt_chunk(const float* __restrict__ src,
                                          __bf16* __restrict__ dst, size_t off,
                                          int tid) {
  const f32x4* p = (const f32x4*)src + off + tid;
  __bf16* q = dst + 4 * (off + tid);
  f32x4 v0 = __builtin_nontemporal_load(p);
  f32x4 v1 = __builtin_nontemporal_load(p + 256);
  f32x4 v2 = __builtin_nontemporal_load(p + 512);
  f32x4 v3 = __builtin_nontemporal_load(p + 768);
  f32x4 v4 = __builtin_nontemporal_load(p + 1024);
  f32x4 v5 = __builtin_nontemporal_load(p + 1280);
  f32x4 v6 = __builtin_nontemporal_load(p + 1536);
  f32x4 v7 = __builtin_nontemporal_load(p + 1792);
  *(bf16x4*)(q + 0 * 1024) = pack4(v0);
  *(bf16x4*)(q + 1 * 1024) = pack4(v1);
  *(bf16x4*)(q + 2 * 1024) = pack4(v2);
  *(bf16x4*)(q + 3 * 1024) = pack4(v3);
  *(bf16x4*)(q + 4 * 1024) = pack4(v4);
  *(bf16x4*)(q + 5 * 1024) = pack4(v5);
  *(bf16x4*)(q + 6 * 1024) = pack4(v6);
  *(bf16x4*)(q + 7 * 1024) = pack4(v7);
}

#define W4 ((size_t)1 << 22)
#define S4 ((size_t)1 << 18)
#define X4 ((size_t)1 << 19)
#define LOGITS_BLOCKS (T_TOK / 4)
#define XCHUNKS ((int)(X4 / 2048))          // 256
#define OCHUNKS 256                          // out zeroing: 2^19 f32x4 / 2048

// ---- fused_pre: router logits (512) + x cvt (256) + out zero (256) -------
__global__ __launch_bounds__(256) void fused_pre(
    const float* __restrict__ x, const float* __restrict__ gw,
    __bf16* __restrict__ xb, float* __restrict__ logits,
    float* __restrict__ out) {
  int tid = threadIdx.x;
  if ((int)blockIdx.x < LOGITS_BLOCKS) {
    int wv = tid >> 6;
    int lane = tid & 63;
    int tok = blockIdx.x * 4 + wv;
    int e = lane >> 2;
    int q = lane & 3;
    const float4* xr = (const float4*)(x + (size_t)tok * HD) + q * 64;
    const float4* wr = (const float4*)(gw + (size_t)e * HD) + q * 64;
    float s0 = 0.f, s1 = 0.f;
#pragma unroll 8
    for (int i = 0; i < 64; i += 2) {
      float4 a0 = xr[i], w0 = wr[i];
      float4 a1 = xr[i + 1], w1v = wr[i + 1];
      s0 += a0.x * w0.x + a0.y * w0.y + a0.z * w0.z + a0.w * w0.w;
      s1 += a1.x * w1v.x + a1.y * w1v.y + a1.z * w1v.z + a1.w * w1v.w;
    }
    float s = s0 + s1;
    s += __shfl_xor(s, 1);
    s += __shfl_xor(s, 2);
    if (q == 0) logits[(size_t)tok * NE + e] = s;
    return;
  }
  if ((int)blockIdx.x < LOGITS_BLOCKS + XCHUNKS) {
    cvt_chunk(x, xb, (size_t)(blockIdx.x - LOGITS_BLOCKS) * 2048, tid);
    return;
  }
  // out zeroing: one 2048-f32x4 (32KB) chunk per block
  size_t f = (size_t)(blockIdx.x - LOGITS_BLOCKS - XCHUNKS) * 2048;
  f32x4* o = (f32x4*)out + f + tid;
  f32x4 z = {0.f, 0.f, 0.f, 0.f};
#pragma unroll
  for (int j = 0; j < 8; ++j) o[j * 256] = z;
}

// ---- router_cvt: block 0 = router_finish body; blocks 1.. = w1/w3/sw cvt --
#define RW_CHUNKS ((int)((2 * W4 + 2 * S4) / 2048))   // 4352
#define RC_GRID 2049

__global__ __launch_bounds__(256) void router_cvt(
    const float* __restrict__ logits, const float* __restrict__ bias,
    int* __restrict__ tile_e, int* __restrict__ tile_e2,
    int* __restrict__ slot_tok, float* __restrict__ slot_w,
    const float* __restrict__ w1, const float* __restrict__ w3,
    const float* __restrict__ sw1, const float* __restrict__ sw3,
    __bf16* __restrict__ w1b, __bf16* __restrict__ w3b) {
  int tid = threadIdx.x;
  if (blockIdx.x != 0) {
    for (size_t c = blockIdx.x - 1; c < RW_CHUNKS; c += RC_GRID - 1) {
      size_t f = c * 2048;
      const float* src;
      __bf16* dst;
      size_t off;
      if (f < W4) { src = w1; dst = w1b; off = f; }
      else if (f < 2 * W4) { src = w3; dst = w3b; off = f - W4; }
      else if (f < 2 * W4 + S4) { src = sw1; dst = w1b + 16 * EXSZ; off = f - 2 * W4; }
      else { src = sw3; dst = w3b + 16 * EXSZ; off = f - 2 * W4 - S4; }
      cvt_chunk(src, dst, off, tid);
    }
    return;
  }

  __shared__ int hist[NE];
  __shared__ int soff[NE + 1];
  __shared__ int fillp[NE];
  __shared__ unsigned lsel[T_TOK];
  __shared__ float4 lw4[T_TOK];

  if (tid < NE) { hist[tid] = 0; fillp[tid] = 0; }
  __syncthreads();

  float bb[NE];
#pragma unroll
  for (int e = 0; e < NE; ++e) bb[e] = bias[e];

  for (int j = 0; j < T_TOK / 256; ++j) {
    int t = tid + 256 * j;
    float lg[NE];
    const float4* lp = (const float4*)(logits + (size_t)t * NE);
#pragma unroll
    for (int q = 0; q < 4; ++q) {
      float4 v = lp[q];
      lg[4 * q] = v.x; lg[4 * q + 1] = v.y; lg[4 * q + 2] = v.z; lg[4 * q + 3] = v.w;
    }
    float b[NE];
#pragma unroll
    for (int e = 0; e < NE; ++e) b[e] = lg[e] + bb[e];

    int selk[TOPK];
    float raw[TOPK];
    unsigned used = 0;
#pragma unroll
    for (int k = 0; k < TOPK; ++k) {
      float best = -3.4e38f;
      int bi = 0;
#pragma unroll
      for (int e = 0; e < NE; ++e) {
        if (!((used >> e) & 1) && b[e] > best) { best = b[e]; bi = e; }
      }
      used |= (1u << bi);
      selk[k] = bi;
      raw[k] = lg[bi];
    }
    float m = raw[0];
#pragma unroll
    for (int k = 1; k < TOPK; ++k) m = fmaxf(m, raw[k]);
    float s = 0.f;
    float w[TOPK];
#pragma unroll
    for (int k = 0; k < TOPK; ++k) { w[k] = __expf(raw[k] - m); s += w[k]; }
    float inv = 1.f / s;
    lsel[t] = (unsigned)selk[0] | ((unsigned)selk[1] << 8) |
              ((unsigned)selk[2] << 16) | ((unsigned)selk[3] << 24);
    lw4[t] = make_float4(w[0] * inv, w[1] * inv, w[2] * inv, w[3] * inv);
#pragma unroll
    for (int k = 0; k < TOPK; ++k) atomicAdd(&hist[selk[k]], 1);
  }
  __syncthreads();

  if (tid == 0) {
    int o = 0;
    for (int e = 0; e < NE; ++e) { soff[e] = o; o += (hist[e] + BM1 - 1) & ~(BM1 - 1); }
    soff[NE] = o;
  }
  __syncthreads();
  int shared_base = soff[NE];
  int total = shared_base + T_TOK;
  for (int tt = tid; tt < MT_MAX; tt += 256) {
    int base = tt * BM;
    int ee = -1;
    if (base < shared_base) {
      ee = 0;
#pragma unroll
      for (int q = 1; q < NE; ++q) if (base >= soff[q]) ee = q;
    } else if (base < total) {
      ee = NE;
    }
    tile_e[tt] = ee;
  }
  for (int tt = tid; tt < MT2_MAX; tt += 256) {
    int base = tt * BM1;
    int ee = -1;
    if (base < shared_base) {
      ee = 0;
#pragma unroll
      for (int q = 1; q < NE; ++q) if (base >= soff[q]) ee = q;
    } else if (base < total) {
      ee = NE;
    }
    tile_e2[tt] = ee;
  }

  for (int j = 0; j < T_TOK / 256; ++j) {
    int t = tid + 256 * j;
    unsigned ps = lsel[t];
    float4 wv = lw4[t];
    int e0 = ps & 255, e1 = (ps >> 8) & 255, e2 = (ps >> 16) & 255, e3 = ps >> 24;
    int p0 = atomicAdd(&fillp[e0], 1);
    slot_tok[soff[e0] + p0] = t; slot_w[soff[e0] + p0] = wv.x;
    int p1 = atomicAdd(&fillp[e1], 1);
    slot_tok[soff[e1] + p1] = t; slot_w[soff[e1] + p1] = wv.y;
    int p2 = atomicAdd(&fillp[e2], 1);
    slot_tok[soff[e2] + p2] = t; slot_w[soff[e2] + p2] = wv.z;
    int p3 = atomicAdd(&fillp[e3], 1);
    slot_tok[soff[e3] + p3] = t; slot_w[soff[e3] + p3] = wv.w;
  }

  for (int s = tid; s < shared_base; s += 256) {
    int e = 0;
#pragma unroll
    for (int q = 1; q < NE; ++q) if (s >= soff[q]) e = q;
    if (s >= soff[e] + hist[e]) { slot_tok[s] = -1; slot_w[s] = 0.f; }
  }
  for (int s = shared_base + tid; s < total; s += 256) {
    slot_tok[s] = s - shared_base;
    slot_w[s] = 1.0f;
  }
}

// ===== pass 1 (r15/r18-proven): 256x128xBK64, 512 thr, 2-sub-phase =========
// + fused w2/sw2 cvt tail blocks (idle-BW backfill).  No setprio (r19: null).
#define P1_BLOCKS (8 * MT2_MAX)             // 512
#define W2CHUNKS ((int)((W4 + S4) / 4096))  // 1088 (512-thr chunks)

__global__ __launch_bounds__(512, 2) void pass1_bf16(
    const __bf16* __restrict__ xb, const int* __restrict__ slot_tok,
    const int* __restrict__ tile_e2, const __bf16* __restrict__ w1b,
    const __bf16* __restrict__ w3b, __bf16* __restrict__ h1,
    const float* __restrict__ w2, const float* __restrict__ sw2,
    __bf16* __restrict__ w2b) {
  int tid = threadIdx.x;
  int bid = blockIdx.x;
  if (bid >= P1_BLOCKS) {
    size_t f = (size_t)(bid - P1_BLOCKS) * 4096;
    const float* src;
    __bf16* dst;
    size_t off;
    if (f < W4) { src = w2; dst = w2b; off = f; }
    else { src = sw2; dst = w2b + 16 * EXSZ; off = f - W4; }
    const f32x4* p = (const f32x4*)src + off + tid;
    __bf16* q = dst + 4 * (off + tid);
    f32x4 v0 = __builtin_nontemporal_load(p);
    f32x4 v1 = __builtin_nontemporal_load(p + 512);
    f32x4 v2 = __builtin_nontemporal_load(p + 1024);
    f32x4 v3 = __builtin_nontemporal_load(p + 1536);
    f32x4 v4 = __builtin_nontemporal_load(p + 2048);
    f32x4 v5 = __builtin_nontemporal_load(p + 2560);
    f32x4 v6 = __builtin_nontemporal_load(p + 3072);
    f32x4 v7 = __builtin_nontemporal_load(p + 3584);
    *(bf16x4*)(q + 0 * 2048) = pack4(v0);
    *(bf16x4*)(q + 1 * 2048) = pack4(v1);
    *(bf16x4*)(q + 2 * 2048) = pack4(v2);
    *(bf16x4*)(q + 3 * 2048) = pack4(v3);
    *(bf16x4*)(q + 4 * 2048) = pack4(v4);
    *(bf16x4*)(q + 5 * 2048) = pack4(v5);
    *(bf16x4*)(q + 6 * 2048) = pack4(v6);
    *(bf16x4*)(q + 7 * 2048) = pack4(v7);
    return;
  }
  int nt = bid & 7;
  int mt = bid >> 3;
  int e = tile_e2[mt];
  if (e < 0) return;
  int n0 = nt * BN1;
  int m0 = mt * BM1;

  const __bf16* wg = w1b + (size_t)e * EXSZ;   // slot 16 = shared expert
  const __bf16* wu = w3b + (size_t)e * EXSZ;

  __shared__ __align__(16) __bf16 As[2][BM1 * BK1];  // 64 KB
  __shared__ __align__(16) __bf16 Bg[2][BN1 * BK1];  // 32 KB
  __shared__ __align__(16) __bf16 Bu[2][BN1 * BK1];  // 32 KB

  const __bf16* gA[4];
#pragma unroll
  for (int j = 0; j < 4; ++j) {
    int id = tid + j * 512;
    int r = id >> 3;
    int c = (id & 7) ^ (r & 7);
    int tok = slot_tok[m0 + r];
    if (tok < 0) tok = 0;
    gA[j] = xb + (size_t)tok * HD + c * 8;
  }
  const __bf16* gG[2];
  const __bf16* gU[2];
#pragma unroll
  for (int j = 0; j < 2; ++j) {
    int id = tid + j * 512;
    int r = id >> 3;
    int c = (id & 7) ^ (r & 7);
    gG[j] = wg + (size_t)(n0 + r) * HD + c * 8;
    gU[j] = wu + (size_t)(n0 + r) * HD + c * 8;
  }

  int wave = tid >> 6, lane = tid & 63;
  int wm = (wave >> 2) * 128;
  int wn = (wave & 3) * 32;
  int l16 = lane & 15, kch = lane >> 4;

  f32x4 accg[8][2] = {};
  f32x4 accu[8][2] = {};

  auto stage = [&](int B, int k0) {   // 8 gloads / thread
#pragma unroll
    for (int j = 0; j < 4; ++j)
      gload16(gA[j] + k0, &As[B][(size_t)(tid + j * 512) * 8]);
#pragma unroll
    for (int j = 0; j < 2; ++j) {
      gload16(gG[j] + k0, &Bg[B][(size_t)(tid + j * 512) * 8]);
      gload16(gU[j] + k0, &Bu[B][(size_t)(tid + j * 512) * 8]);
    }
  };

#pragma unroll 1
  for (int k = 0; k < NK1; ++k) {
    int buf = k & 1;
    if (k == 0) stage(0, 0);
    if (k + 1 < NK1) {
      stage(buf ^ 1, (k + 1) * BK1);
      asm volatile("s_waitcnt vmcnt(8)" ::: "memory");
    } else {
      asm volatile("s_waitcnt vmcnt(0)" ::: "memory");
    }
    __builtin_amdgcn_s_barrier();
    __builtin_amdgcn_sched_barrier(0);

#pragma unroll
    for (int s = 0; s < 2; ++s) {
      bf16x8 af[8], gf[2], uf[2];
#pragma unroll
      for (int i = 0; i < 8; ++i) {
        int R = wm + i * 16 + l16;
        int c = s * 4 + kch;
        af[i] = *(const bf16x8*)(&As[buf][R * BK1 + ((c ^ (R & 7)) * 8)]);
      }
#pragma unroll
      for (int i = 0; i < 2; ++i) {
        int R = wn + i * 16 + l16;
        int c = s * 4 + kch;
        gf[i] = *(const bf16x8*)(&Bg[buf][R * BK1 + ((c ^ (R & 7)) * 8)]);
        uf[i] = *(const bf16x8*)(&Bu[buf][R * BK1 + ((c ^ (R & 7)) * 8)]);
      }
      asm volatile("s_waitcnt lgkmcnt(0)" ::: "memory");
      if (s == 1) __builtin_amdgcn_s_barrier();
      __builtin_amdgcn_sched_barrier(0);         // rule #18
#pragma unroll
      for (int mi = 0; mi < 8; ++mi)
#pragma unroll
        for (int ni = 0; ni < 2; ++ni) {
          accg[mi][ni] = mfma16(af[mi], gf[ni], accg[mi][ni]);
          accu[mi][ni] = mfma16(af[mi], uf[ni], accu[mi][ni]);
        }
    }
  }

#pragma unroll
  for (int mi = 0; mi < 8; ++mi) {
#pragma unroll
    for (int ni = 0; ni < 2; ++ni) {
#pragma unroll
      for (int j = 0; j < 4; ++j) {
        int row = m0 + wm + mi * 16 + kch * 4 + j;
        int col = n0 + wn + ni * 16 + l16;
        float g = accg[mi][ni][j];
        float u = accu[mi][ni][j];
        float hv = (g / (1.f + __expf(-g))) * u;
        h1[(size_t)row * ID + col] = (__bf16)hv;
      }
    }
  }
}

// ===== pass 2 (r14-proven all-bf16): 128²/BK32, (256,3), vmcnt(4) ==========
__global__ __launch_bounds__(256, 3) void pass2_bf16(
    const __bf16* __restrict__ h1, const int* __restrict__ slot_tok,
    const float* __restrict__ slot_w, const int* __restrict__ tile_e,
    const __bf16* __restrict__ w2b, float* __restrict__ out) {
  int mt = blockIdx.y;
  int e = tile_e[mt];
  if (e < 0) return;
  int n0 = blockIdx.x * BN;
  int m0 = mt * BM;

  const __bf16* wd = w2b + (size_t)e * EXSZ;   // slot 16 = shared expert

  __shared__ __align__(16) __bf16 As[2][BM * BK];
  __shared__ __align__(16) __bf16 Bs[2][BN * BK];

  int tid = threadIdx.x;
  int r0 = tid >> 2, r1 = r0 + 64;
  int c8 = ((tid & 3) ^ ((r0 >> 1) & 3)) * 8;
  const __bf16* gA0 = h1 + (size_t)(m0 + r0) * ID + c8;
  const __bf16* gA1 = h1 + (size_t)(m0 + r1) * ID + c8;
  const __bf16* gB0 = wd + (size_t)(n0 + r0) * ID + c8;
  const __bf16* gB1 = wd + (size_t)(n0 + r1) * ID + c8;

  int wave = tid >> 6, lane = tid & 63;
  int wm = (wave >> 1) * 64, wn = (wave & 1) * 64;
  int l16 = lane & 15, kch = lane >> 4;
  int kk8 = (kch ^ ((l16 >> 1) & 3)) * 8;

  f32x4 acc[4][4] = {};

  auto stage = [&](int B, int k0) {
    gload16(gA0 + k0, &As[B][(size_t)tid * 8]);
    gload16(gA1 + k0, &As[B][(size_t)(tid + 256) * 8]);
    gload16(gB0 + k0, &Bs[B][(size_t)tid * 8]);
    gload16(gB1 + k0, &Bs[B][(size_t)(tid + 256) * 8]);
  };
  auto body = [&](int B) {
    bf16x8 af[4], bf[4];
#pragma unroll
    for (int i = 0; i < 4; ++i) {
      af[i] = *(const bf16x8*)(&As[B][(wm + i * 16 + l16) * BK + kk8]);
      bf[i] = *(const bf16x8*)(&Bs[B][(wn + i * 16 + l16) * BK + kk8]);
    }
    asm volatile("s_waitcnt lgkmcnt(0)" ::: "memory");
    __builtin_amdgcn_s_barrier();
    __builtin_amdgcn_sched_barrier(0);
#pragma unroll
    for (int mi = 0; mi < 4; ++mi)
#pragma unroll
      for (int ni = 0; ni < 4; ++ni)
        acc[mi][ni] = mfma16(af[mi], bf[ni], acc[mi][ni]);
  };

  stage(0, 0);
#pragma unroll 1
  for (int k = 0; k < ID / BK - 1; ++k) {
    int cur = k & 1;
    stage(cur ^ 1, (k + 1) * BK);
    asm volatile("s_waitcnt vmcnt(4)" ::: "memory");
    __builtin_amdgcn_s_barrier();
    __builtin_amdgcn_sched_barrier(0);
    body(cur);
  }
  asm volatile("s_waitcnt vmcnt(0)" ::: "memory");
  __builtin_amdgcn_s_barrier();
  __builtin_amdgcn_sched_barrier(0);
  body((ID / BK - 1) & 1);

#pragma unroll
  for (int mi = 0; mi < 4; ++mi) {
#pragma unroll
    for (int j = 0; j < 4; ++j) {
      int row = m0 + wm + mi * 16 + kch * 4 + j;
      int token = slot_tok[row];
      if (token < 0) continue;
      float wgt = slot_w[row];
#pragma unroll
      for (int ni = 0; ni < 4; ++ni) {
        int col = n0 + wn + ni * 16 + l16;
        atomicAdd(out + (size_t)token * HD + col, wgt * acc[mi][ni][j]);
      }
    }
  }
}

// ---------------- launcher ----------------
extern "C" void kernel_launch(void* const* d_in, const int* in_sizes, int n_in,
                              void* d_out, int out_size, void* d_ws, size_t ws_size,
                              hipStream_t stream) {
  const float* x = (const float*)d_in[0];
  const float* gate_w = (const float*)d_in[1];
  const float* ebias = (const float*)d_in[2];
  const float* w1 = (const float*)d_in[3];
  const float* w2 = (const float*)d_in[4];
  const float* w3 = (const float*)d_in[5];
  const float* sw1 = (const float*)d_in[6];
  const float* sw2 = (const float*)d_in[7];
  const float* sw3 = (const float*)d_in[8];
  float* out = (float*)d_out;

  char* ws = (char*)d_ws;
  int* tile_e = (int*)(ws + WS_TILE_E);
  int* tile_e2 = (int*)(ws + WS_TILE_E2);
  float* logits = (float*)(ws + WS_LOGITS);
  int* slot_tok = (int*)(ws + WS_SLOT_TOK);
  float* slot_w = (float*)(ws + WS_SLOT_W);
  __bf16* h1 = (__bf16*)(ws + WS_H1);
  __bf16* xb = (__bf16*)(ws + WS_XB);
  __bf16* w1b = (__bf16*)(ws + WS_W1B);       // 17 experts
  __bf16* w3b = w1b + 17 * EXSZ;              // 17 experts
  __bf16* w2b = w3b + 17 * EXSZ;              // 17 experts

  fused_pre<<<LOGITS_BLOCKS + XCHUNKS + OCHUNKS, 256, 0, stream>>>(
      x, gate_w, xb, logits, out);
  router_cvt<<<RC_GRID, 256, 0, stream>>>(logits, ebias, tile_e, tile_e2,
                                          slot_tok, slot_w, w1, w3, sw1, sw3,
                                          w1b, w3b);
  pass1_bf16<<<P1_BLOCKS + W2CHUNKS, 512, 0, stream>>>(
      xb, slot_tok, tile_e2, w1b, w3b, h1, w2, sw2, w2b);
  pass2_bf16<<<dim3(HD / BN, MT_MAX), 256, 0, stream>>>(
      h1, slot_tok, slot_w, tile_e, w2b, out);
}

// Round 21
// 206.690 us; speedup vs baseline: 1.0377x; 1.0082x over previous
//
#include <hip/hip_runtime.h>
#include <cstddef>
#include <cstdint>

#define T_TOK 2048
#define HD 1024
#define ID 1024
#define NE 16
#define TOPK 4
#define BM 128          // pass2 m-tile
#define BN2 256         // pass2 n-tile
#define BK 32
#define BM1 256         // pass1 tile
#define BN1 128
#define BK1 64
#define NK1 (HD / BK1)  // 16
#define MT_MAX 112      // 128-row tiles (pass2)
#define MT2_MAX 64      // 256-row tiles (pass1)
#define SLOT_CAP 16384

typedef float f32x4 __attribute__((ext_vector_type(4)));
typedef __bf16 bf16x8 __attribute__((ext_vector_type(8)));
typedef __bf16 bf16x4 __attribute__((ext_vector_type(4)));

// ---- workspace layout (bytes) ----
// w1b/w3b/w2b each hold 17 experts (slot 16 = shared expert).
#define WS_TILE_E 256                                   // int[MT_MAX]
#define WS_TILE_E2 2048                                 // int[MT2_MAX]
#define WS_LOGITS 4096                                  // float[2048*16]
#define WS_SLOT_TOK (WS_LOGITS + T_TOK * NE * 4)        // int[SLOT_CAP]
#define WS_SLOT_W (WS_SLOT_TOK + SLOT_CAP * 4)          // float[SLOT_CAP]
#define WS_H1 (WS_SLOT_W + SLOT_CAP * 4)                // bf16[SLOT_CAP][ID]
#define WS_XB (WS_H1 + (size_t)SLOT_CAP * ID * 2)       // bf16[T][H]
#define WS_W1B (WS_XB + (size_t)T_TOK * HD * 2)         // bf16 17*I*H
#define EXSZ ((size_t)ID * HD)

__device__ __forceinline__ f32x4 mfma16(bf16x8 a, bf16x8 b, f32x4 c) {
  return __builtin_amdgcn_mfma_f32_16x16x32_bf16(a, b, c, 0, 0, 0);
}

__device__ __forceinline__ bf16x4 pack4(f32x4 a) {
  bf16x4 o;
  o[0] = (__bf16)a[0]; o[1] = (__bf16)a[1]; o[2] = (__bf16)a[2]; o[3] = (__bf16)a[3];
  return o;
}

// async global(16B/lane) -> LDS, linear dest (m97 pattern)
__device__ __forceinline__ void gload16(const __bf16* g, __bf16* l) {
  __builtin_amdgcn_global_load_lds(
      (const __attribute__((address_space(1))) uint32_t*)g,
      (__attribute__((address_space(3))) uint32_t*)l, 16, 0, 0);
}

// 2048-f32x4 chunk cvt (256 thr): lane-adjacent 16B loads, MLP=8
__device__ __forceinline__ void cvt_chunk(const float* __restrict__ src,
                                          __bf16* __restrict__ dst, size_t off,
                                          int tid) {
  const f32x4* p = (const f32x4*)src + off + tid;
  __bf16* q = dst + 4 * (off + tid);
  f32x4 v0 = __builtin_nontemporal_load(p);
  f32x4 v1 = __builtin_nontemporal_load(p + 256);
  f32x4 v2 = __builtin_nontemporal_load(p + 512);
  f32x4 v3 = __builtin_nontemporal_load(p + 768);
  f32x4 v4 = __builtin_nontemporal_load(p + 1024);
  f32x4 v5 = __builtin_nontemporal_load(p + 1280);
  f32x4 v6 = __builtin_nontemporal_load(p + 1536);
  f32x4 v7 = __builtin_nontemporal_load(p + 1792);
  *(bf16x4*)(q + 0 * 1024) = pack4(v0);
  *(bf16x4*)(q + 1 * 1024) = pack4(v1);
  *(bf16x4*)(q + 2 * 1024) = pack4(v2);
  *(bf16x4*)(q + 3 * 1024) = pack4(v3);
  *(bf16x4*)(q + 4 * 1024) = pack4(v4);
  *(bf16x4*)(q + 5 * 1024) = pack4(v5);
  *(bf16x4*)(q + 6 * 1024) = pack4(v6);
  *(bf16x4*)(q + 7 * 1024) = pack4(v7);
}

#define W4 ((size_t)1 << 22)
#define S4 ((size_t)1 << 18)
#define X4 ((size_t)1 << 19)
#define LOGITS_BLOCKS (T_TOK / 4)
#define XCHUNKS ((int)(X4 / 2048))          // 256
#define OCHUNKS 256                          // out zeroing

// ---- fused_pre: router logits (512) + x cvt (256) + out zero (256) -------
__global__ __launch_bounds__(256) void fused_pre(
    const float* __restrict__ x, const float* __restrict__ gw,
    __bf16* __restrict__ xb, float* __restrict__ logits,
    float* __restrict__ out) {
  int tid = threadIdx.x;
  if ((int)blockIdx.x < LOGITS_BLOCKS) {
    int wv = tid >> 6;
    int lane = tid & 63;
    int tok = blockIdx.x * 4 + wv;
    int e = lane >> 2;
    int q = lane & 3;
    const float4* xr = (const float4*)(x + (size_t)tok * HD) + q * 64;
    const float4* wr = (const float4*)(gw + (size_t)e * HD) + q * 64;
    float s0 = 0.f, s1 = 0.f;
#pragma unroll 8
    for (int i = 0; i < 64; i += 2) {
      float4 a0 = xr[i], w0 = wr[i];
      float4 a1 = xr[i + 1], w1v = wr[i + 1];
      s0 += a0.x * w0.x + a0.y * w0.y + a0.z * w0.z + a0.w * w0.w;
      s1 += a1.x * w1v.x + a1.y * w1v.y + a1.z * w1v.z + a1.w * w1v.w;
    }
    float s = s0 + s1;
    s += __shfl_xor(s, 1);
    s += __shfl_xor(s, 2);
    if (q == 0) logits[(size_t)tok * NE + e] = s;
    return;
  }
  if ((int)blockIdx.x < LOGITS_BLOCKS + XCHUNKS) {
    cvt_chunk(x, xb, (size_t)(blockIdx.x - LOGITS_BLOCKS) * 2048, tid);
    return;
  }
  size_t f = (size_t)(blockIdx.x - LOGITS_BLOCKS - XCHUNKS) * 2048;
  f32x4* o = (f32x4*)out + f + tid;
  f32x4 z = {0.f, 0.f, 0.f, 0.f};
#pragma unroll
  for (int j = 0; j < 8; ++j) o[j * 256] = z;
}

// ---- router_cvt: block 0 = router_finish body; blocks 1.. = w1/w3/sw cvt --
#define RW_CHUNKS ((int)((2 * W4 + 2 * S4) / 2048))   // 4352
#define RC_GRID 2049

__global__ __launch_bounds__(256) void router_cvt(
    const float* __restrict__ logits, const float* __restrict__ bias,
    int* __restrict__ tile_e, int* __restrict__ tile_e2,
    int* __restrict__ slot_tok, float* __restrict__ slot_w,
    const float* __restrict__ w1, const float* __restrict__ w3,
    const float* __restrict__ sw1, const float* __restrict__ sw3,
    __bf16* __restrict__ w1b, __bf16* __restrict__ w3b) {
  int tid = threadIdx.x;
  if (blockIdx.x != 0) {
    for (size_t c = blockIdx.x - 1; c < RW_CHUNKS; c += RC_GRID - 1) {
      size_t f = c * 2048;
      const float* src;
      __bf16* dst;
      size_t off;
      if (f < W4) { src = w1; dst = w1b; off = f; }
      else if (f < 2 * W4) { src = w3; dst = w3b; off = f - W4; }
      else if (f < 2 * W4 + S4) { src = sw1; dst = w1b + 16 * EXSZ; off = f - 2 * W4; }
      else { src = sw3; dst = w3b + 16 * EXSZ; off = f - 2 * W4 - S4; }
      cvt_chunk(src, dst, off, tid);
    }
    return;
  }

  __shared__ int hist[NE];
  __shared__ int soff[NE + 1];
  __shared__ int fillp[NE];
  __shared__ unsigned lsel[T_TOK];
  __shared__ float4 lw4[T_TOK];

  if (tid < NE) { hist[tid] = 0; fillp[tid] = 0; }
  __syncthreads();

  float bb[NE];
#pragma unroll
  for (int e = 0; e < NE; ++e) bb[e] = bias[e];

  for (int j = 0; j < T_TOK / 256; ++j) {
    int t = tid + 256 * j;
    float lg[NE];
    const float4* lp = (const float4*)(logits + (size_t)t * NE);
#pragma unroll
    for (int q = 0; q < 4; ++q) {
      float4 v = lp[q];
      lg[4 * q] = v.x; lg[4 * q + 1] = v.y; lg[4 * q + 2] = v.z; lg[4 * q + 3] = v.w;
    }
    float b[NE];
#pragma unroll
    for (int e = 0; e < NE; ++e) b[e] = lg[e] + bb[e];

    int selk[TOPK];
    float raw[TOPK];
    unsigned used = 0;
#pragma unroll
    for (int k = 0; k < TOPK; ++k) {
      float best = -3.4e38f;
      int bi = 0;
#pragma unroll
      for (int e = 0; e < NE; ++e) {
        if (!((used >> e) & 1) && b[e] > best) { best = b[e]; bi = e; }
      }
      used |= (1u << bi);
      selk[k] = bi;
      raw[k] = lg[bi];
    }
    float m = raw[0];
#pragma unroll
    for (int k = 1; k < TOPK; ++k) m = fmaxf(m, raw[k]);
    float s = 0.f;
    float w[TOPK];
#pragma unroll
    for (int k = 0; k < TOPK; ++k) { w[k] = __expf(raw[k] - m); s += w[k]; }
    float inv = 1.f / s;
    lsel[t] = (unsigned)selk[0] | ((unsigned)selk[1] << 8) |
              ((unsigned)selk[2] << 16) | ((unsigned)selk[3] << 24);
    lw4[t] = make_float4(w[0] * inv, w[1] * inv, w[2] * inv, w[3] * inv);
#pragma unroll
    for (int k = 0; k < TOPK; ++k) atomicAdd(&hist[selk[k]], 1);
  }
  __syncthreads();

  if (tid == 0) {
    int o = 0;
    for (int e = 0; e < NE; ++e) { soff[e] = o; o += (hist[e] + BM1 - 1) & ~(BM1 - 1); }
    soff[NE] = o;
  }
  __syncthreads();
  int shared_base = soff[NE];
  int total = shared_base + T_TOK;
  for (int tt = tid; tt < MT_MAX; tt += 256) {
    int base = tt * BM;
    int ee = -1;
    if (base < shared_base) {
      ee = 0;
#pragma unroll
      for (int q = 1; q < NE; ++q) if (base >= soff[q]) ee = q;
    } else if (base < total) {
      ee = NE;
    }
    tile_e[tt] = ee;
  }
  for (int tt = tid; tt < MT2_MAX; tt += 256) {
    int base = tt * BM1;
    int ee = -1;
    if (base < shared_base) {
      ee = 0;
#pragma unroll
      for (int q = 1; q < NE; ++q) if (base >= soff[q]) ee = q;
    } else if (base < total) {
      ee = NE;
    }
    tile_e2[tt] = ee;
  }

  for (int j = 0; j < T_TOK / 256; ++j) {
    int t = tid + 256 * j;
    unsigned ps = lsel[t];
    float4 wv = lw4[t];
    int e0 = ps & 255, e1 = (ps >> 8) & 255, e2 = (ps >> 16) & 255, e3 = ps >> 24;
    int p0 = atomicAdd(&fillp[e0], 1);
    slot_tok[soff[e0] + p0] = t; slot_w[soff[e0] + p0] = wv.x;
    int p1 = atomicAdd(&fillp[e1], 1);
    slot_tok[soff[e1] + p1] = t; slot_w[soff[e1] + p1] = wv.y;
    int p2 = atomicAdd(&fillp[e2], 1);
    slot_tok[soff[e2] + p2] = t; slot_w[soff[e2] + p2] = wv.z;
    int p3 = atomicAdd(&fillp[e3], 1);
    slot_tok[soff[e3] + p3] = t; slot_w[soff[e3] + p3] = wv.w;
  }

  for (int s = tid; s < shared_base; s += 256) {
    int e = 0;
#pragma unroll
    for (int q = 1; q < NE; ++q) if (s >= soff[q]) e = q;
    if (s >= soff[e] + hist[e]) { slot_tok[s] = -1; slot_w[s] = 0.f; }
  }
  for (int s = shared_base + tid; s < total; s += 256) {
    slot_tok[s] = s - shared_base;
    slot_w[s] = 1.0f;
  }
}

// ===== pass 1 (r15/r18-proven): 256x128xBK64, 512 thr, 2-sub-phase =========
#define P1_BLOCKS (8 * MT2_MAX)             // 512
#define W2CHUNKS ((int)((W4 + S4) / 4096))  // 1088 (512-thr chunks)

__global__ __launch_bounds__(512, 2) void pass1_bf16(
    const __bf16* __restrict__ xb, const int* __restrict__ slot_tok,
    const int* __restrict__ tile_e2, const __bf16* __restrict__ w1b,
    const __bf16* __restrict__ w3b, __bf16* __restrict__ h1,
    const float* __restrict__ w2, const float* __restrict__ sw2,
    __bf16* __restrict__ w2b) {
  int tid = threadIdx.x;
  int bid = blockIdx.x;
  if (bid >= P1_BLOCKS) {
    size_t f = (size_t)(bid - P1_BLOCKS) * 4096;
    const float* src;
    __bf16* dst;
    size_t off;
    if (f < W4) { src = w2; dst = w2b; off = f; }
    else { src = sw2; dst = w2b + 16 * EXSZ; off = f - W4; }
    const f32x4* p = (const f32x4*)src + off + tid;
    __bf16* q = dst + 4 * (off + tid);
    f32x4 v0 = __builtin_nontemporal_load(p);
    f32x4 v1 = __builtin_nontemporal_load(p + 512);
    f32x4 v2 = __builtin_nontemporal_load(p + 1024);
    f32x4 v3 = __builtin_nontemporal_load(p + 1536);
    f32x4 v4 = __builtin_nontemporal_load(p + 2048);
    f32x4 v5 = __builtin_nontemporal_load(p + 2560);
    f32x4 v6 = __builtin_nontemporal_load(p + 3072);
    f32x4 v7 = __builtin_nontemporal_load(p + 3584);
    *(bf16x4*)(q + 0 * 2048) = pack4(v0);
    *(bf16x4*)(q + 1 * 2048) = pack4(v1);
    *(bf16x4*)(q + 2 * 2048) = pack4(v2);
    *(bf16x4*)(q + 3 * 2048) = pack4(v3);
    *(bf16x4*)(q + 4 * 2048) = pack4(v4);
    *(bf16x4*)(q + 5 * 2048) = pack4(v5);
    *(bf16x4*)(q + 6 * 2048) = pack4(v6);
    *(bf16x4*)(q + 7 * 2048) = pack4(v7);
    return;
  }
  int nt = bid & 7;
  int mt = bid >> 3;
  int e = tile_e2[mt];
  if (e < 0) return;
  int n0 = nt * BN1;
  int m0 = mt * BM1;

  const __bf16* wg = w1b + (size_t)e * EXSZ;   // slot 16 = shared expert
  const __bf16* wu = w3b + (size_t)e * EXSZ;

  __shared__ __align__(16) __bf16 As[2][BM1 * BK1];  // 64 KB
  __shared__ __align__(16) __bf16 Bg[2][BN1 * BK1];  // 32 KB
  __shared__ __align__(16) __bf16 Bu[2][BN1 * BK1];  // 32 KB

  const __bf16* gA[4];
#pragma unroll
  for (int j = 0; j < 4; ++j) {
    int id = tid + j * 512;
    int r = id >> 3;
    int c = (id & 7) ^ (r & 7);
    int tok = slot_tok[m0 + r];
    if (tok < 0) tok = 0;
    gA[j] = xb + (size_t)tok * HD + c * 8;
  }
  const __bf16* gG[2];
  const __bf16* gU[2];
#pragma unroll
  for (int j = 0; j < 2; ++j) {
    int id = tid + j * 512;
    int r = id >> 3;
    int c = (id & 7) ^ (r & 7);
    gG[j] = wg + (size_t)(n0 + r) * HD + c * 8;
    gU[j] = wu + (size_t)(n0 + r) * HD + c * 8;
  }

  int wave = tid >> 6, lane = tid & 63;
  int wm = (wave >> 2) * 128;
  int wn = (wave & 3) * 32;
  int l16 = lane & 15, kch = lane >> 4;

  f32x4 accg[8][2] = {};
  f32x4 accu[8][2] = {};

  auto stage = [&](int B, int k0) {   // 8 gloads / thread
#pragma unroll
    for (int j = 0; j < 4; ++j)
      gload16(gA[j] + k0, &As[B][(size_t)(tid + j * 512) * 8]);
#pragma unroll
    for (int j = 0; j < 2; ++j) {
      gload16(gG[j] + k0, &Bg[B][(size_t)(tid + j * 512) * 8]);
      gload16(gU[j] + k0, &Bu[B][(size_t)(tid + j * 512) * 8]);
    }
  };

#pragma unroll 1
  for (int k = 0; k < NK1; ++k) {
    int buf = k & 1;
    if (k == 0) stage(0, 0);
    if (k + 1 < NK1) {
      stage(buf ^ 1, (k + 1) * BK1);
      asm volatile("s_waitcnt vmcnt(8)" ::: "memory");
    } else {
      asm volatile("s_waitcnt vmcnt(0)" ::: "memory");
    }
    __builtin_amdgcn_s_barrier();
    __builtin_amdgcn_sched_barrier(0);

#pragma unroll
    for (int s = 0; s < 2; ++s) {
      bf16x8 af[8], gf[2], uf[2];
#pragma unroll
      for (int i = 0; i < 8; ++i) {
        int R = wm + i * 16 + l16;
        int c = s * 4 + kch;
        af[i] = *(const bf16x8*)(&As[buf][R * BK1 + ((c ^ (R & 7)) * 8)]);
      }
#pragma unroll
      for (int i = 0; i < 2; ++i) {
        int R = wn + i * 16 + l16;
        int c = s * 4 + kch;
        gf[i] = *(const bf16x8*)(&Bg[buf][R * BK1 + ((c ^ (R & 7)) * 8)]);
        uf[i] = *(const bf16x8*)(&Bu[buf][R * BK1 + ((c ^ (R & 7)) * 8)]);
      }
      asm volatile("s_waitcnt lgkmcnt(0)" ::: "memory");
      if (s == 1) __builtin_amdgcn_s_barrier();
      __builtin_amdgcn_sched_barrier(0);         // rule #18
#pragma unroll
      for (int mi = 0; mi < 8; ++mi)
#pragma unroll
        for (int ni = 0; ni < 2; ++ni) {
          accg[mi][ni] = mfma16(af[mi], gf[ni], accg[mi][ni]);
          accu[mi][ni] = mfma16(af[mi], uf[ni], accu[mi][ni]);
        }
    }
  }

#pragma unroll
  for (int mi = 0; mi < 8; ++mi) {
#pragma unroll
    for (int ni = 0; ni < 2; ++ni) {
#pragma unroll
      for (int j = 0; j < 4; ++j) {
        int row = m0 + wm + mi * 16 + kch * 4 + j;
        int col = n0 + wn + ni * 16 + l16;
        float g = accg[mi][ni][j];
        float u = accu[mi][ni][j];
        float hv = (g / (1.f + __expf(-g))) * u;
        h1[(size_t)row * ID + col] = (__bf16)hv;
      }
    }
  }
}

// ===== pass 2: 128x256xBK32, 512 thr / 8 waves (2Mx4N of 64x64), 48KB ======
// Same 24KB/step staging as a 256-tile (2x intensity of 128²) but keeps
// 2 blocks/CU (r16 lesson: 96KB 256-tile lost occupancy).  acc[4][4]=64
// regs at (512,2), uniform 3 gloads/thread -> vmcnt(3).
__global__ __launch_bounds__(512, 2) void pass2_bf16(
    const __bf16* __restrict__ h1, const int* __restrict__ slot_tok,
    const float* __restrict__ slot_w, const int* __restrict__ tile_e,
    const __bf16* __restrict__ w2b, float* __restrict__ out) {
  int mt = blockIdx.y;
  int e = tile_e[mt];
  if (e < 0) return;
  int n0 = blockIdx.x * BN2;
  int m0 = mt * BM;

  const __bf16* wd = w2b + (size_t)e * EXSZ;   // slot 16 = shared expert

  __shared__ __align__(16) __bf16 As[2][BM * BK];    // 16 KB
  __shared__ __align__(16) __bf16 Bs[2][BN2 * BK];   // 32 KB

  int tid = threadIdx.x;
  // A: 512 slots (1/thread); row = id>>2, phys chunk id&3 holds global
  // chunk (id&3)^((row>>1)&3)  (r14 swizzle)
  int ra = tid >> 2;
  int ca = (tid & 3) ^ ((ra >> 1) & 3);
  const __bf16* gA0 = h1 + (size_t)(m0 + ra) * ID + ca * 8;
  // B: 1024 slots (2/thread)
  const __bf16* gB[2];
#pragma unroll
  for (int j = 0; j < 2; ++j) {
    int id = tid + j * 512;
    int r = id >> 2;
    int c = (id & 3) ^ ((r >> 1) & 3);
    gB[j] = wd + (size_t)(n0 + r) * ID + c * 8;
  }

  int wave = tid >> 6, lane = tid & 63;
  int wm = (wave >> 2) * 64;    // 2 M-halves of 64 rows
  int wn = (wave & 3) * 64;     // 4 N-quarters of 64 cols
  int l16 = lane & 15, kch = lane >> 4;
  int kk8 = (kch ^ ((l16 >> 1) & 3)) * 8;

  f32x4 acc[4][4] = {};

  auto stage = [&](int B, int k0) {   // 3 gloads / thread
    gload16(gA0 + k0, &As[B][(size_t)tid * 8]);
#pragma unroll
    for (int j = 0; j < 2; ++j)
      gload16(gB[j] + k0, &Bs[B][(size_t)(tid + j * 512) * 8]);
  };
  auto body = [&](int B) {
    bf16x8 af[4], bf[4];
#pragma unroll
    for (int i = 0; i < 4; ++i) {
      af[i] = *(const bf16x8*)(&As[B][(wm + i * 16 + l16) * BK + kk8]);
      bf[i] = *(const bf16x8*)(&Bs[B][(wn + i * 16 + l16) * BK + kk8]);
    }
    asm volatile("s_waitcnt lgkmcnt(0)" ::: "memory");
    __builtin_amdgcn_s_barrier();
    __builtin_amdgcn_sched_barrier(0);
#pragma unroll
    for (int mi = 0; mi < 4; ++mi)
#pragma unroll
      for (int ni = 0; ni < 4; ++ni)
        acc[mi][ni] = mfma16(af[mi], bf[ni], acc[mi][ni]);
  };

  stage(0, 0);
#pragma unroll 1
  for (int k = 0; k < ID / BK - 1; ++k) {
    int cur = k & 1;
    stage(cur ^ 1, (k + 1) * BK);
    asm volatile("s_waitcnt vmcnt(3)" ::: "memory");
    __builtin_amdgcn_s_barrier();
    __builtin_amdgcn_sched_barrier(0);
    body(cur);
  }
  asm volatile("s_waitcnt vmcnt(0)" ::: "memory");
  __builtin_amdgcn_s_barrier();
  __builtin_amdgcn_sched_barrier(0);
  body((ID / BK - 1) & 1);

#pragma unroll
  for (int mi = 0; mi < 4; ++mi) {
#pragma unroll
    for (int j = 0; j < 4; ++j) {
      int row = m0 + wm + mi * 16 + kch * 4 + j;
      int token = slot_tok[row];
      if (token < 0) continue;
      float wgt = slot_w[row];
#pragma unroll
      for (int ni = 0; ni < 4; ++ni) {
        int col = n0 + wn + ni * 16 + l16;
        atomicAdd(out + (size_t)token * HD + col, wgt * acc[mi][ni][j]);
      }
    }
  }
}

// ---------------- launcher ----------------
extern "C" void kernel_launch(void* const* d_in, const int* in_sizes, int n_in,
                              void* d_out, int out_size, void* d_ws, size_t ws_size,
                              hipStream_t stream) {
  const float* x = (const float*)d_in[0];
  const float* gate_w = (const float*)d_in[1];
  const float* ebias = (const float*)d_in[2];
  const float* w1 = (const float*)d_in[3];
  const float* w2 = (const float*)d_in[4];
  const float* w3 = (const float*)d_in[5];
  const float* sw1 = (const float*)d_in[6];
  const float* sw2 = (const float*)d_in[7];
  const float* sw3 = (const float*)d_in[8];
  float* out = (float*)d_out;

  char* ws = (char*)d_ws;
  int* tile_e = (int*)(ws + WS_TILE_E);
  int* tile_e2 = (int*)(ws + WS_TILE_E2);
  float* logits = (float*)(ws + WS_LOGITS);
  int* slot_tok = (int*)(ws + WS_SLOT_TOK);
  float* slot_w = (float*)(ws + WS_SLOT_W);
  __bf16* h1 = (__bf16*)(ws + WS_H1);
  __bf16* xb = (__bf16*)(ws + WS_XB);
  __bf16* w1b = (__bf16*)(ws + WS_W1B);       // 17 experts
  __bf16* w3b = w1b + 17 * EXSZ;              // 17 experts
  __bf16* w2b = w3b + 17 * EXSZ;              // 17 experts

  fused_pre<<<LOGITS_BLOCKS + XCHUNKS + OCHUNKS, 256, 0, stream>>>(
      x, gate_w, xb, logits, out);
  router_cvt<<<RC_GRID, 256, 0, stream>>>(logits, ebias, tile_e, tile_e2,
                                          slot_tok, slot_w, w1, w3, sw1, sw3,
                                          w1b, w3b);
  pass1_bf16<<<P1_BLOCKS + W2CHUNKS, 512, 0, stream>>>(
      xb, slot_tok, tile_e2, w1b, w3b, h1, w2, sw2, w2b);
  pass2_bf16<<<dim3(HD / BN2, MT_MAX), 512, 0, stream>>>(
      h1, slot_tok, slot_w, tile_e, w2b, out);
}